// Round 1
// baseline (189.369 us; speedup 1.0000x reference)
//
#include <hip/hip_runtime.h>

// Problem constants (match reference setup_inputs)
#define BB   64
#define CIN  2048
#define COUT 2048
#define TT   128

typedef int i32x4 __attribute__((ext_vector_type(4)));

__device__ __forceinline__ void async16(char* lds_dst, const char* g_src) {
    __builtin_amdgcn_global_load_lds(
        (const __attribute__((address_space(1))) void*)g_src,
        (__attribute__((address_space(3))) void*)lds_dst,
        16, 0, 0);
}

// LDS-only barrier: waits ds ops, does NOT drain vmcnt (keeps stores/prefetch in flight)
__device__ __forceinline__ void lds_barrier() {
    asm volatile("s_waitcnt lgkmcnt(0)" ::: "memory");
    __builtin_amdgcn_s_barrier();
}

// --- Fused prep: masked weights -> i8 [COUT][CIN], spikes -> i8 A[(b*T+t)][c]
// (unchanged from verified kernel)
__global__ void prep_kernel(const float* __restrict__ spikes,
                            const float* __restrict__ w,
                            const float* __restrict__ msk,
                            char* __restrict__ A,
                            char* __restrict__ Wm) {
    __shared__ float tile[64][33];
    int bid = blockIdx.x;
    int tid = threadIdx.x;

    if (bid < 1024) {
        size_t i = ((size_t)bid * 256 + tid) * 16;
        int out4[4];
#pragma unroll
        for (int q = 0; q < 4; ++q) {
            float4 a = *(const float4*)(w + i + q * 4);
            float4 m = *(const float4*)(msk + i + q * 4);
            int b0 = (int)(char)(int)(a.x * m.x);
            int b1 = (int)(char)(int)(a.y * m.y);
            int b2 = (int)(char)(int)(a.z * m.z);
            int b3 = (int)(char)(int)(a.w * m.w);
            out4[q] = (b0 & 0xFF) | ((b1 & 0xFF) << 8) | ((b2 & 0xFF) << 16) | (b3 << 24);
        }
        *(int4*)(Wm + i) = *(int4*)out4;
        return;
    }

    bid -= 1024;
    int cc = bid & 31;
    int tt = (bid >> 5) & 3;
    int b  = bid >> 7;
    int c0 = cc * 64, t0 = tt * 32;

    int t4 = tid & 7;
    int cr = tid >> 3;
#pragma unroll
    for (int s = 0; s < 2; ++s) {
        int c = cr + s * 32;
        float4 v = *(const float4*)(spikes + ((size_t)b * CIN + c0 + c) * TT + t0 + t4 * 4);
        tile[c][t4 * 4 + 0] = v.x;
        tile[c][t4 * 4 + 1] = v.y;
        tile[c][t4 * 4 + 2] = v.z;
        tile[c][t4 * 4 + 3] = v.w;
    }
    __syncthreads();

    int tw_ = tid >> 4;
    int cq  = tid & 15;
#pragma unroll
    for (int s2 = 0; s2 < 2; ++s2) {
        int tw = tw_ + s2 * 16;
        int packed = 0;
#pragma unroll
        for (int q = 0; q < 4; ++q)
            packed |= ((tile[cq * 4 + q][tw] != 0.f) ? 1 : 0) << (8 * q);
        *(int*)(A + ((size_t)(b * TT) + t0 + tw) * CIN + c0 + cq * 4) = packed;
    }
}

// --- 256x256 8-phase-style i8 GEMM (BK=128, mfma_i32_16x16x64_i8, exact)
//     + LIF scan epilogue in two 128-channel chunks + coalesced store ---
// 512 threads = 8 waves (2M x 4N); per-wave output 128x64; 1 block/CU.
__global__ void __launch_bounds__(512)
snn_gemm_scan(const char* __restrict__ A,    // [8192][2048] i8
              const char* __restrict__ Wm,   // [2048][2048] i8
              const int* __restrict__ scale_exp,
              const int* __restrict__ thr_exp,
              float* __restrict__ out) {     // [B][COUT][T]
    __shared__ __align__(16) union {
        struct { char A[2][32768]; char B[2][32768]; } st;   // 128 KB dbuf staging
        float c[256 * 130];                                  // 133.1 KB scan buffer
    } lds;
    __shared__ unsigned pb[256 * 4];

    const int tid  = threadIdx.x;
    const int lane = tid & 63;
    const int w    = tid >> 6;
    const int wr   = w >> 2;   // 0..1: row half (= batch within tile)
    const int wc   = w & 3;    // 0..3: col quarter

    // ni = bid&7: default round-robin puts same-ni blocks on one XCD ->
    // the 512 KB B panel stays L2-resident per XCD; A streams via L3.
    const int bid = blockIdx.x;
    const int ni = bid & 7;
    const int mi = bid >> 3;          // 0..31
    const int m0 = mi * 256;
    const int n0 = ni * 256;

    // staging: linear LDS dest (global_load_lds constraint), source column
    // XOR-pre-swizzled (chunk ^= row&7) so ds_read_b128 frags are 2-way (free).
    const int srow = tid >> 3;                    // 0..63 (+64 per i)
    const int schk = (tid & 7) ^ (srow & 7);      // round-invariant (64%8==0)
    const char* gA = A  + (size_t)(m0 + srow) * CIN + schk * 16;
    const char* gB = Wm + (size_t)(n0 + srow) * CIN + schk * 16;

    // fragment read offsets (byte addr in a 256x128B tile); k-step flips bit6
    const int mrow = lane & 15, kc = lane >> 4;
    unsigned offA[8], offB[4];
#pragma unroll
    for (int mf = 0; mf < 8; ++mf) {
        int r = wr * 128 + mf * 16 + mrow;
        offA[mf] = (unsigned)(r * 128 + (kc ^ (r & 7)) * 16);
    }
#pragma unroll
    for (int nf = 0; nf < 4; ++nf) {
        int r = wc * 64 + nf * 16 + mrow;
        offB[nf] = (unsigned)(r * 128 + (kc ^ (r & 7)) * 16);
    }

    i32x4 acc[8][4] = {};

    // prologue: stage K-tile 0 into buf 0
#pragma unroll
    for (int i = 0; i < 4; ++i)
        async16(lds.st.A[0] + (unsigned)(tid * 16 + i * 8192), gA + (size_t)(i * 64) * CIN);
#pragma unroll
    for (int i = 0; i < 4; ++i)
        async16(lds.st.B[0] + (unsigned)(tid * 16 + i * 8192), gB + (size_t)(i * 64) * CIN);
    asm volatile("s_waitcnt vmcnt(0)" ::: "memory");
    __builtin_amdgcn_s_barrier();

#pragma unroll 2
    for (int t = 0; t < 16; ++t) {
        char* cA = lds.st.A[t & 1];
        char* cB = lds.st.B[t & 1];
        char* nA = lds.st.A[(t + 1) & 1];
        char* nB = lds.st.B[(t + 1) & 1];
        const size_t kof = (size_t)(t + 1) * 128;
        i32x4 av[4][2], b0[2][2], b1[2][2];

        // ---- P0: read A-lo + B-lo; prefetch next A-tile; MFMA Q(lo,lo)
#pragma unroll
        for (int mf = 0; mf < 4; ++mf)
#pragma unroll
            for (int ks = 0; ks < 2; ++ks)
                av[mf][ks] = *(const i32x4*)(cA + (offA[mf] ^ (ks << 6)));
#pragma unroll
        for (int nf = 0; nf < 2; ++nf)
#pragma unroll
            for (int ks = 0; ks < 2; ++ks)
                b0[nf][ks] = *(const i32x4*)(cB + (offB[nf] ^ (ks << 6)));
        if (t < 15) {
#pragma unroll
            for (int i = 0; i < 4; ++i)
                async16(nA + (unsigned)(tid * 16 + i * 8192), gA + kof + (size_t)(i * 64) * CIN);
        }
        __builtin_amdgcn_s_barrier();
        __builtin_amdgcn_s_setprio(1);
#pragma unroll
        for (int mf = 0; mf < 4; ++mf)
#pragma unroll
            for (int nf = 0; nf < 2; ++nf)
#pragma unroll
                for (int ks = 0; ks < 2; ++ks)
                    acc[mf][nf] = __builtin_amdgcn_mfma_i32_16x16x64_i8(
                        av[mf][ks], b0[nf][ks], acc[mf][nf], 0, 0, 0);
        __builtin_amdgcn_s_setprio(0);
        __builtin_amdgcn_s_barrier();

        // ---- P1: read B-hi; prefetch next B-tile; MFMA Q(lo,hi)
#pragma unroll
        for (int nf = 0; nf < 2; ++nf)
#pragma unroll
            for (int ks = 0; ks < 2; ++ks)
                b1[nf][ks] = *(const i32x4*)(cB + (offB[2 + nf] ^ (ks << 6)));
        if (t < 15) {
#pragma unroll
            for (int i = 0; i < 4; ++i)
                async16(nB + (unsigned)(tid * 16 + i * 8192), gB + kof + (size_t)(i * 64) * CIN);
        }
        __builtin_amdgcn_s_barrier();
        __builtin_amdgcn_s_setprio(1);
#pragma unroll
        for (int mf = 0; mf < 4; ++mf)
#pragma unroll
            for (int nf = 0; nf < 2; ++nf)
#pragma unroll
                for (int ks = 0; ks < 2; ++ks)
                    acc[mf][2 + nf] = __builtin_amdgcn_mfma_i32_16x16x64_i8(
                        av[mf][ks], b1[nf][ks], acc[mf][2 + nf], 0, 0, 0);
        __builtin_amdgcn_s_setprio(0);
        __builtin_amdgcn_s_barrier();

        // ---- P2: read A-hi (reuse av regs); MFMA Q(hi,hi)
#pragma unroll
        for (int mf = 0; mf < 4; ++mf)
#pragma unroll
            for (int ks = 0; ks < 2; ++ks)
                av[mf][ks] = *(const i32x4*)(cA + (offA[4 + mf] ^ (ks << 6)));
        __builtin_amdgcn_s_barrier();
        __builtin_amdgcn_s_setprio(1);
#pragma unroll
        for (int mf = 0; mf < 4; ++mf)
#pragma unroll
            for (int nf = 0; nf < 2; ++nf)
#pragma unroll
                for (int ks = 0; ks < 2; ++ks)
                    acc[4 + mf][2 + nf] = __builtin_amdgcn_mfma_i32_16x16x64_i8(
                        av[mf][ks], b1[nf][ks], acc[4 + mf][2 + nf], 0, 0, 0);
        __builtin_amdgcn_s_setprio(0);
        __builtin_amdgcn_s_barrier();

        // ---- P3: MFMA Q(hi,lo) (b0 still live); tile-boundary vmcnt -
        // prefetch loads were issued 2-3 phases ago, so this wait is ~free.
        __builtin_amdgcn_s_setprio(1);
#pragma unroll
        for (int mf = 0; mf < 4; ++mf)
#pragma unroll
            for (int nf = 0; nf < 2; ++nf)
#pragma unroll
                for (int ks = 0; ks < 2; ++ks)
                    acc[4 + mf][nf] = __builtin_amdgcn_mfma_i32_16x16x64_i8(
                        av[mf][ks], b0[nf][ks], acc[4 + mf][nf], 0, 0, 0);
        __builtin_amdgcn_s_setprio(0);
        asm volatile("s_waitcnt vmcnt(0)" ::: "memory");
        __builtin_amdgcn_s_barrier();
    }

    // ---- Epilogue: LIF scan in two 128-channel chunks through LDS ----
    const float thr = exp2f((float)thr_exp[0]);
#pragma unroll
    for (int p = 0; p < 2; ++p) {
        // stage C chunk (cols p*128..p*128+127) as f32 into lds.c[256][130]
        if ((wc >> 1) == p) {
            const int rb  = (lane >> 4) * 4;
            const int cb  = lane & 15;
            const int chb = (wc & 1) * 64;
#pragma unroll
            for (int mf = 0; mf < 8; ++mf)
#pragma unroll
                for (int nf = 0; nf < 4; ++nf)
#pragma unroll
                    for (int r = 0; r < 4; ++r)
                        lds.c[(wr * 128 + mf * 16 + rb + r) * 130 + chb + nf * 16 + cb] =
                            (float)acc[mf][nf][r];
        }
        lds_barrier();

        // serial LIF scan: 256 threads = 2 batches x 128 channels, 128 t each
        if (tid < 256) {
            const int batch = tid >> 7, ch = tid & 127;
            const float scale = exp2f((float)scale_exp[n0 + p * 128 + ch]);
            float a = 0.f;
#pragma unroll
            for (int q = 0; q < 4; ++q) {
                unsigned bq = 0u;
#pragma unroll 8
                for (int j = 0; j < 32; ++j) {
                    a += lds.c[(batch * 128 + q * 32 + j) * 130 + ch] * scale;
                    unsigned s = (a >= thr) ? 1u : 0u;
                    if (s) a = 0.f;
                    bq |= s << j;
                }
                pb[tid * 4 + q] = bq;
            }
        }
        lds_barrier();

        // coalesced float4 stores: out[2*mi+batch][n0 + p*128 + co][t]
        const int t4 = tid & 31, u = tid >> 5;
#pragma unroll
        for (int s2 = 0; s2 < 16; ++s2) {
            int pair = s2 * 16 + u;               // 0..255 = batch*128+co
            int batch = pair >> 7, co = pair & 127;
            unsigned wb  = pb[pair * 4 + (t4 >> 3)];
            unsigned nib = (wb >> ((t4 & 7) * 4)) & 0xFu;
            float4 v;
            v.x = (float)(nib & 1u);
            v.y = (float)((nib >> 1) & 1u);
            v.z = (float)((nib >> 2) & 1u);
            v.w = (float)((nib >> 3) & 1u);
            *(float4*)(out + ((size_t)((2 * mi + batch) * COUT + n0 + p * 128 + co)) * TT
                       + t4 * 4) = v;
        }
    }
}

extern "C" void kernel_launch(void* const* d_in, const int* in_sizes, int n_in,
                              void* d_out, int out_size, void* d_ws, size_t ws_size,
                              hipStream_t stream) {
    const float* spikes  = (const float*)d_in[0];
    const float* weights = (const float*)d_in[1];
    const float* mask    = (const float*)d_in[2];
    const int*   scale_e = (const int*)d_in[3];
    const int*   thr_e   = (const int*)d_in[4];
    float* out = (float*)d_out;

    // workspace: A i8 [8192][2048] = 16 MB, Wm i8 [2048][2048] = 4 MB
    char* Ai8 = (char*)d_ws;
    char* Wm  = (char*)d_ws + (size_t)BB * TT * CIN;

    prep_kernel<<<1024 + BB * 4 * 32, 256, 0, stream>>>(spikes, weights, mask, Ai8, Wm);
    snn_gemm_scan<<<BB * (COUT / 256) / 2, 512, 0, stream>>>(Ai8, Wm, scale_e, thr_e, out);
}